// Round 2
// baseline (719.743 us; speedup 1.0000x reference)
//
#include <hip/hip_runtime.h>
#include <hip/hip_bf16.h>

#define TT_    8
#define HEADS_ 8
#define NB_    147
#define NPIX   32768                // 8*64*64
#define NTASK  (NPIX*NB_)           // 4,816,896
#define ROWS_  (NPIX + 512)         // x rows + W rows, concatenated for prepack
#define NBLK_SLICE 2352             // blocks per t-slice (4096*147/256)

typedef _Float16 half8 __attribute__((ext_vector_type(8)));
typedef _Float16 h2    __attribute__((ext_vector_type(2)));
typedef float    f32x4 __attribute__((ext_vector_type(4)));

__device__ __forceinline__ int reflect64(int v) {
  int m = v % 126;
  m += (m >> 31) & 126;             // floor-mod into [0,126)
  return (m > 63) ? (126 - m) : m;
}

__device__ __forceinline__ float dot2f(h2 a, h2 b, float c) {
#if __has_builtin(__builtin_amdgcn_fdot2)
  return __builtin_amdgcn_fdot2(a, b, c, false);
#else
  return c + (float)a[0]*(float)b[0] + (float)a[1]*(float)b[1];
#endif
}

// DPP quad-perm cross-lane adds (within aligned quads of 4 lanes).
__device__ __forceinline__ float dpp_xor1(float x) {
  int r = __builtin_amdgcn_mov_dpp(__builtin_bit_cast(int, x), 0xB1, 0xF, 0xF, true);
  return __builtin_bit_cast(float, r);
}
__device__ __forceinline__ float dpp_xor2(float x) {
  int r = __builtin_amdgcn_mov_dpp(__builtin_bit_cast(int, x), 0x4E, 0xF, 0xF, true);
  return __builtin_bit_cast(float, r);
}

// ---- Kernel 0: prepack x||W (rows x 256 f32) into fragment-native f16 ----
__global__ __launch_bounds__(256) void prepack(
    const float* __restrict__ x, const float* __restrict__ wqk,
    _Float16* __restrict__ outp) {
  int o  = (int)blockIdx.x * 256 + (int)threadIdx.x;   // 0 .. ROWS_*32
  int r  = o & 15, quad = (o >> 4) & 3, ks = (o >> 6) & 7, mt = o >> 9;
  int row = mt * 16 + r;
  const float* src = (row < NPIX) ? (x + (size_t)row * 256)
                                  : (wqk + (size_t)(row - NPIX) * 256);
  int col = (ks * 4 + quad) * 8;
  float4 a = *(const float4*)(src + col);
  float4 b = *(const float4*)(src + col + 4);
  half8 h;
  h[0]=(_Float16)a.x; h[1]=(_Float16)a.y; h[2]=(_Float16)a.z; h[3]=(_Float16)a.w;
  h[4]=(_Float16)b.x; h[5]=(_Float16)b.y; h[6]=(_Float16)b.z; h[7]=(_Float16)b.w;
  ((half8*)outp)[o] = h;
}

// ---- Kernel 1: qk GEMM from prepacked fragments (no LDS) ----
__global__ __launch_bounds__(256) void qk_gemm(
    const _Float16* __restrict__ Ap,
    _Float16* __restrict__ qws, _Float16* __restrict__ kws) {
  const half8* A8 = (const half8*)Ap;
  const half8* B8 = (const half8*)(Ap + (size_t)NPIX * 256);
  int bid  = (int)blockIdx.x;
  int mblk = bid >> 3, nblk = bid & 7;
  int lane = (int)threadIdx.x & 63, wv = (int)threadIdx.x >> 6;
  int wm = mblk * 64 + (wv >> 1) * 32;
  int wn = nblk * 64 + (wv & 1) * 32;
  int r = lane & 15, quad = lane >> 4;

  half8 af[2][8], bf[2][8];
#pragma unroll
  for (int im = 0; im < 2; im++) {
    int mt = (wm >> 4) + im;
#pragma unroll
    for (int ks = 0; ks < 8; ks++)
      af[im][ks] = A8[((mt * 8 + ks) * 4 + quad) * 16 + r];
  }
#pragma unroll
  for (int in = 0; in < 2; in++) {
    int nt = (wn >> 4) + in;
#pragma unroll
    for (int ks = 0; ks < 8; ks++)
      bf[in][ks] = B8[((nt * 8 + ks) * 4 + quad) * 16 + r];
  }

  f32x4 acc[2][2] = {};
#pragma unroll
  for (int ks = 0; ks < 8; ks++)
#pragma unroll
    for (int im = 0; im < 2; im++)
#pragma unroll
      for (int in = 0; in < 2; in++)
        acc[im][in] = __builtin_amdgcn_mfma_f32_16x16x32_f16(
            af[im][ks], bf[in][ks], acc[im][in], 0, 0, 0);

  _Float16* dst = (wn < 256) ? qws : kws;
  int nsub = (wn < 256) ? 0 : 256;
#pragma unroll
  for (int im = 0; im < 2; im++)
#pragma unroll
    for (int in = 0; in < 2; in++) {
      int n = wn + in * 16 + r - nsub;
#pragma unroll
      for (int reg = 0; reg < 4; reg++) {
        int m = wm + im * 16 + quad * 4 + reg;
        dst[(size_t)m * 256 + n] = (_Float16)acc[im][in][reg];
      }
    }
}

// ---- Kernel 2: neighborhood attention, head-split for L2 residency ----
// Grid 2*18816. Each block: 256 tasks x 4 heads (one 256B half of each k row).
// XCD j (= blockIdx&7): half = j>>2 (heads 0-3 / 4-7), slices {2*(j&3), +1}.
// Per-phase k working set = 3 slices x 4096 rows x 256B = 3.1 MB < 4 MB L2.
__global__ __launch_bounds__(256) void attn_kernel(
    const float* __restrict__ flows,
    const _Float16* __restrict__ qws, const _Float16* __restrict__ kws,
    float* __restrict__ out) {
  __shared__ int      s_info[256];
  __shared__ __attribute__((aligned(16))) _Float16 s_q[3 * 16 * 8];    // [pix][chunk 0..15][8 f16]
  __shared__ __attribute__((aligned(16))) float    s_attn[4 * 260];    // [head_lo][task], pad 260
  __shared__ __attribute__((aligned(16))) float    s_flow[768];        // [task*3+c]

  int i    = (int)blockIdx.x;
  int xcd  = i & 7;
  int r_   = i >> 3;                       // 0..4703 within XCD
  int half = xcd >> 2;                     // 0: heads 0-3, 1: heads 4-7
  int hi   = (r_ >= NBLK_SLICE) ? 1 : 0;
  int slice = 2 * (xcd & 3) + hi;
  int q_   = r_ - hi * NBLK_SLICE;
  int blk  = slice * NBLK_SLICE + q_;      // logical block in task space
  int tx   = (int)threadIdx.x;
  int btid0 = blk * 256;
  int p0 = (int)((unsigned)btid0 / 147u);

  { // ---- phase 1: per-task setup (one thread per task) ----
    int tid = btid0 + tx;
    unsigned p = (unsigned)tid / 147u;
    int nb = tid - (int)(p * 147u);
    int t = (int)(p >> 12), hw = (int)(p & 4095u);
    int h = hw >> 6, w = hw & 63;
    int slot = nb / 49;
    int rr = nb - slot * 49;
    int a = rr / 7, b = rr - a * 7;
    int tp = t, di = 0, dj = 0;
    if (slot > 0) {
      int si = slot - 1;
      di = (int)rintf(flows[(size_t)((t * 2 + si) * 2 + 0) * 4096 + hw]);
      dj = (int)rintf(flows[(size_t)((t * 2 + si) * 2 + 1) * 4096 + hw]);
      tp = (slot == 1) ? ((t + 1 < TT_) ? t + 1 : t - 2)
                       : ((t - 1 >= 0)  ? t - 1 : t + 2);
    }
    int li = reflect64(h + di + a - 3);
    int lj = reflect64(w + dj + b - 3);
    int kidx = (tp << 12) + (li << 6) + lj;           // < 2^15
    int pixloc = (int)p - p0;                          // 0..2
    s_info[tx] = kidx | (pixloc << 20);
    s_flow[tx * 3 + 0] = (float)(tp - t);
    s_flow[tx * 3 + 1] = (float)(li - h);
    s_flow[tx * 3 + 2] = (float)(lj - w);
  }
  if (tx < 48) { // ---- q staging: 3 pixels x 256B (this half's 16 chunks) ----
    int pix = tx >> 4, s = tx & 15;                    // s: 16B chunk within half
    int p = p0 + pix; if (p > NPIX - 1) p = NPIX - 1;
    half8 v = *(const half8*)(qws + (size_t)p * 256 + (half * 16 + s) * 8);
    ((half8*)s_q)[pix * 16 + s] = v;
  }
  __syncthreads();

  // ---- phase 2: 8 lanes per task, 2 c-iters (4 heads) ----
  int lane = tx & 63, wv = tx >> 6;
  int j = lane & 7, g = lane >> 3;
  const float scale = 0.17677669529663687f;            // 32^-0.5
#pragma unroll
  for (int it = 0; it < 8; it++) {
    int tb = wv * 64 + it * 8 + g;
    int info = s_info[tb];
    int kidx = info & 0xFFFFF;
    int pixloc = info >> 20;
    // global chunk index = half*16 + cc*8 + j  (4 consecutive lanes = one 64B line)
    const half8* kp = (const half8*)(kws + ((size_t)kidx << 8)) + half * 16 + j;
    const half8* qp = ((const half8*)s_q) + pixloc * 16 + j;
    float acc[2];
#pragma unroll
    for (int cc = 0; cc < 2; cc++) {
      half8 k8 = kp[cc * 8];
      half8 q8 = qp[cc * 8];
      float s = 0.f;
#pragma unroll
      for (int u = 0; u < 8; u += 2) {
        h2 ka = { k8[u], k8[u + 1] };
        h2 qa = { q8[u], q8[u + 1] };
        s = dot2f(ka, qa, s);
      }
      acc[cc] = s;
    }
#pragma unroll
    for (int cc = 0; cc < 2; cc++) {
      float t = acc[cc];
      t += dpp_xor1(t);
      t += dpp_xor2(t);                                // quad sum: full head dot
      if ((lane & 3) == 0)
        s_attn[(2 * cc + ((lane >> 2) & 1)) * 260 + tb] = t * scale;
    }
  }
  __syncthreads();

  // ---- coalesced nontemporal stores from LDS ----
  const f32x4* sa4 = (const f32x4*)s_attn;             // row stride 65 float4
  {
    int hh = tx >> 6, idx = tx & 63;                   // 4 heads x 64 float4
    f32x4 v = sa4[hh * 65 + idx];
    __builtin_nontemporal_store(v,
        (f32x4*)(out + (size_t)(half * 4 + hh) * NTASK + btid0) + idx);
  }
  float* fo = out + (size_t)HEADS_ * NTASK;
  const f32x4* sf4 = (const f32x4*)s_flow;
#pragma unroll
  for (int o = 0; o < 3; o++) {                        // 4 head-copies x 192 float4
    int gg = tx + o * 256;                             // 0..767
    int hh = gg / 192, idx = gg - hh * 192;
    f32x4 v = sf4[idx];
    __builtin_nontemporal_store(v,
        (f32x4*)(fo + (size_t)(half * 4 + hh) * NTASK * 3 + (size_t)btid0 * 3) + idx);
  }
}

extern "C" void kernel_launch(void* const* d_in, const int* in_sizes, int n_in,
                              void* d_out, int out_size, void* d_ws, size_t ws_size,
                              hipStream_t stream) {
  const float* x     = (const float*)d_in[0];   // (8,64,64,256) f32
  const float* flows = (const float*)d_in[1];   // (1,8,2,2,64,64) f32
  const float* wqk   = (const float*)d_in[2];   // (512,256) f32
  float* out = (float*)d_out;

  _Float16* qws = (_Float16*)d_ws;                       // 32768*256 f16
  _Float16* kws = qws + (size_t)NPIX * 256;              // 32768*256 f16
  _Float16* Ap  = kws + (size_t)NPIX * 256;              // 33280*256 f16 fragments

  prepack<<<dim3(ROWS_ * 32 / 256), dim3(256), 0, stream>>>(x, wqk, Ap);
  qk_gemm<<<dim3(4096), dim3(256), 0, stream>>>(Ap, qws, kws);
  attn_kernel<<<dim3(2 * NTASK / 256), dim3(256), 0, stream>>>(flows, qws, kws, out);
}

// Round 3
// 660.703 us; speedup vs baseline: 1.0894x; 1.0894x over previous
//
#include <hip/hip_runtime.h>
#include <hip/hip_bf16.h>

#define TT_    8
#define HEADS_ 8
#define NB_    147
#define NPIX   32768                // 8*64*64
#define NTASK  (NPIX*NB_)           // 4,816,896
#define ROWS_  (NPIX + 512)         // x rows + W rows, concatenated for prepack

typedef _Float16 half8 __attribute__((ext_vector_type(8)));
typedef _Float16 h2    __attribute__((ext_vector_type(2)));
typedef float    f32x4 __attribute__((ext_vector_type(4)));

__device__ __forceinline__ int reflect64(int v) {
  int m = v % 126;
  m += (m >> 31) & 126;             // floor-mod into [0,126)
  return (m > 63) ? (126 - m) : m;
}

__device__ __forceinline__ float dot2f(h2 a, h2 b, float c) {
#if __has_builtin(__builtin_amdgcn_fdot2)
  return __builtin_amdgcn_fdot2(a, b, c, false);
#else
  return c + (float)a[0]*(float)b[0] + (float)a[1]*(float)b[1];
#endif
}

// DPP quad-perm cross-lane adds (within aligned quads of 4 lanes).
__device__ __forceinline__ float dpp_xor1(float x) {
  int r = __builtin_amdgcn_mov_dpp(__builtin_bit_cast(int, x), 0xB1, 0xF, 0xF, true);
  return __builtin_bit_cast(float, r);
}
__device__ __forceinline__ float dpp_xor2(float x) {
  int r = __builtin_amdgcn_mov_dpp(__builtin_bit_cast(int, x), 0x4E, 0xF, 0xF, true);
  return __builtin_bit_cast(float, r);
}

// ---- Kernel 0: prepack x||W (rows x 256 f32) into fragment-native f16 ----
// 16B chunk id o: r=o&15, quad=(o>>4)&3, ks=(o>>6)&7, mt=o>>9.
// Chunk holds row (mt*16+r), cols [(ks*4+quad)*8, +8) as f16.
__global__ __launch_bounds__(256) void prepack(
    const float* __restrict__ x, const float* __restrict__ wqk,
    _Float16* __restrict__ outp) {
  int o  = (int)blockIdx.x * 256 + (int)threadIdx.x;   // 0 .. ROWS_*32
  int r  = o & 15, quad = (o >> 4) & 3, ks = (o >> 6) & 7, mt = o >> 9;
  int row = mt * 16 + r;
  const float* src = (row < NPIX) ? (x + (size_t)row * 256)
                                  : (wqk + (size_t)(row - NPIX) * 256);
  int col = (ks * 4 + quad) * 8;
  float4 a = *(const float4*)(src + col);
  float4 b = *(const float4*)(src + col + 4);
  half8 h;
  h[0]=(_Float16)a.x; h[1]=(_Float16)a.y; h[2]=(_Float16)a.z; h[3]=(_Float16)a.w;
  h[4]=(_Float16)b.x; h[5]=(_Float16)b.y; h[6]=(_Float16)b.z; h[7]=(_Float16)b.w;
  ((half8*)outp)[o] = h;
}

// ---- Kernel 1: qk GEMM, 64x64 per wave (4x4 MFMA sub-tiles) ----
// grid 1024: mblk = bid>>2 (128-row m-tile), nblk = bid&3 (128-col n-tile).
// 4 waves: 64x64 each. ks-outer loop keeps VGPR bounded; fragment traffic
// halves vs 32x32 wave tiles (8B loaded per output B -> 4B).
__global__ __launch_bounds__(256) void qk_gemm(
    const _Float16* __restrict__ Ap,
    _Float16* __restrict__ qws, _Float16* __restrict__ kws) {
  const half8* A8 = (const half8*)Ap;
  const half8* B8 = (const half8*)(Ap + (size_t)NPIX * 256);
  int bid  = (int)blockIdx.x;
  int mblk = bid >> 2, nblk = bid & 3;
  int lane = (int)threadIdx.x & 63, wv = (int)threadIdx.x >> 6;
  int wm = mblk * 128 + (wv >> 1) * 64;
  int wn = nblk * 128 + (wv & 1) * 64;
  int r = lane & 15, quad = lane >> 4;

  f32x4 acc[4][4] = {};
#pragma unroll
  for (int ks = 0; ks < 8; ks++) {
    half8 af[4], bf[4];
#pragma unroll
    for (int im = 0; im < 4; im++)
      af[im] = A8[((((wm >> 4) + im) * 8 + ks) * 4 + quad) * 16 + r];
#pragma unroll
    for (int in = 0; in < 4; in++)
      bf[in] = B8[((((wn >> 4) + in) * 8 + ks) * 4 + quad) * 16 + r];
#pragma unroll
    for (int im = 0; im < 4; im++)
#pragma unroll
      for (int in = 0; in < 4; in++)
        acc[im][in] = __builtin_amdgcn_mfma_f32_16x16x32_f16(
            af[im], bf[in], acc[im][in], 0, 0, 0);
  }

  // n-tile is uniformly q (nblk<2) or k: no divergence.
  _Float16* dst = (wn < 256) ? qws : kws;
  int nsub = (wn < 256) ? 0 : 256;
#pragma unroll
  for (int im = 0; im < 4; im++)
#pragma unroll
    for (int in = 0; in < 4; in++) {
      int n = wn + in * 16 + r - nsub;
#pragma unroll
      for (int reg = 0; reg < 4; reg++) {
        int m = wm + im * 16 + quad * 4 + reg;
        dst[(size_t)m * 256 + n] = (_Float16)acc[im][in][reg];
      }
    }
}

// ---- Kernel 2: neighborhood attention (R1 structure + q-load hoist) ----
// Block = 256 tasks. Phase 1: one thread per task computes setup -> LDS.
// Phase 2: 8 lanes per task. Lane j, iter c reads contiguous 16B chunk
// (c*8+j) of the 512B k row: 4 consecutive lanes cover one 64B line ->
// HW coalesces to 1 request/line (request-count floor). Head h = 2c+(j>>2)
// partials recombined via DPP quad adds; lanes j==0/4 write heads.
__global__ __launch_bounds__(256) void attn_kernel(
    const float* __restrict__ flows,
    const _Float16* __restrict__ qws, const _Float16* __restrict__ kws,
    float* __restrict__ out) {
  __shared__ int      s_info[256];
  __shared__ __attribute__((aligned(16))) _Float16 s_q[3 * 32 * 8];    // [pix][chunk 0..31][8 f16]
  __shared__ __attribute__((aligned(16))) float    s_attn[8 * 260];    // [head][task], pad 260
  __shared__ __attribute__((aligned(16))) float    s_flow[768];        // [task*3+c]

  // XCD swizzle: grid 18816 = 8*2352, contiguous task range per XCD.
  int nbq = (int)gridDim.x >> 3;
  int blk = ((int)blockIdx.x & 7) * nbq + ((int)blockIdx.x >> 3);
  int tx  = (int)threadIdx.x;
  int btid0 = blk * 256;
  int p0 = (int)((unsigned)btid0 / 147u);

  // ---- q staging loads issued EARLY (latency hides under phase-1 VALU) ----
  half8 vq = {};
  int qslot = -1;
  if (tx < 96) {
    int pix = tx >> 5, s = tx & 31;                    // s: 16B chunk of q row
    int p = p0 + pix; if (p > NPIX - 1) p = NPIX - 1;
    vq = *(const half8*)(qws + (size_t)p * 256 + s * 8);
    qslot = pix * 32 + s;
  }

  { // ---- phase 1: per-task setup (one thread per task) ----
    int tid = btid0 + tx;
    unsigned p = (unsigned)tid / 147u;
    int nb = tid - (int)(p * 147u);
    int t = (int)(p >> 12), hw = (int)(p & 4095u);
    int h = hw >> 6, w = hw & 63;
    int slot = nb / 49;
    int rr = nb - slot * 49;
    int a = rr / 7, b = rr - a * 7;
    int tp = t, di = 0, dj = 0;
    if (slot > 0) {
      int si = slot - 1;
      di = (int)rintf(flows[(size_t)((t * 2 + si) * 2 + 0) * 4096 + hw]);
      dj = (int)rintf(flows[(size_t)((t * 2 + si) * 2 + 1) * 4096 + hw]);
      tp = (slot == 1) ? ((t + 1 < TT_) ? t + 1 : t - 2)
                       : ((t - 1 >= 0)  ? t - 1 : t + 2);
    }
    int li = reflect64(h + di + a - 3);
    int lj = reflect64(w + dj + b - 3);
    int kidx = (tp << 12) + (li << 6) + lj;           // < 2^15
    int pixloc = (int)p - p0;                          // 0..2
    s_info[tx] = kidx | (pixloc << 20);
    s_flow[tx * 3 + 0] = (float)(tp - t);
    s_flow[tx * 3 + 1] = (float)(li - h);
    s_flow[tx * 3 + 2] = (float)(lj - w);
  }
  if (qslot >= 0) ((half8*)s_q)[qslot] = vq;
  __syncthreads();

  // ---- phase 2 ----
  int lane = tx & 63, wv = tx >> 6;
  int j = lane & 7, g = lane >> 3;
  const float scale = 0.17677669529663687f;            // 32^-0.5
#pragma unroll
  for (int it = 0; it < 8; it++) {
    int tb = wv * 64 + it * 8 + g;
    int info = s_info[tb];
    int kidx = info & 0xFFFFF;
    int pixloc = info >> 20;
    const half8* kp = (const half8*)(kws + ((size_t)kidx << 8)) + j;   // chunk j
    const half8* qp = ((const half8*)s_q) + pixloc * 32 + j;
    float acc[4];
#pragma unroll
    for (int c = 0; c < 4; c++) {
      half8 k8 = kp[c * 8];                            // chunk c*8+j: 4 lanes/line
      half8 q8 = qp[c * 8];
      float s = 0.f;
#pragma unroll
      for (int u = 0; u < 8; u += 2) {
        h2 ka = { k8[u], k8[u + 1] };
        h2 qa = { q8[u], q8[u + 1] };
        s = dot2f(ka, qa, s);
      }
      acc[c] = s;
    }
#pragma unroll
    for (int c = 0; c < 4; c++) {
      float t = acc[c];
      t += dpp_xor1(t);
      t += dpp_xor2(t);                                // quad sum: full head dot
      if ((lane & 3) == 0)
        s_attn[(2 * c + ((lane >> 2) & 1)) * 260 + tb] = t * scale;
    }
  }
  __syncthreads();

  // ---- coalesced nontemporal stores from LDS (don't thrash L2 for k-gather) ----
  const f32x4* sa4 = (const f32x4*)s_attn;             // row stride 65 float4
#pragma unroll
  for (int o = 0; o < 2; o++) {
    int gg = tx + o * 256;                             // 0..511
    int hh = gg >> 6, idx = gg & 63;
    f32x4 v = sa4[hh * 65 + idx];
    __builtin_nontemporal_store(v, (f32x4*)(out + (size_t)hh * NTASK + btid0) + idx);
  }
  float* fo = out + (size_t)HEADS_ * NTASK;
  const f32x4* sf4 = (const f32x4*)s_flow;
#pragma unroll
  for (int o = 0; o < 6; o++) {
    int gg = tx + o * 256;                             // 0..1535
    int hh = gg / 192, idx = gg - hh * 192;
    f32x4 v = sf4[idx];
    __builtin_nontemporal_store(v, (f32x4*)(fo + (size_t)hh * NTASK * 3 + (size_t)btid0 * 3) + idx);
  }
}

extern "C" void kernel_launch(void* const* d_in, const int* in_sizes, int n_in,
                              void* d_out, int out_size, void* d_ws, size_t ws_size,
                              hipStream_t stream) {
  const float* x     = (const float*)d_in[0];   // (8,64,64,256) f32
  const float* flows = (const float*)d_in[1];   // (1,8,2,2,64,64) f32
  const float* wqk   = (const float*)d_in[2];   // (512,256) f32
  float* out = (float*)d_out;

  _Float16* qws = (_Float16*)d_ws;                       // 32768*256 f16
  _Float16* kws = qws + (size_t)NPIX * 256;              // 32768*256 f16
  _Float16* Ap  = kws + (size_t)NPIX * 256;              // 33280*256 f16 fragments

  prepack<<<dim3(ROWS_ * 32 / 256), dim3(256), 0, stream>>>(x, wqk, Ap);
  qk_gemm<<<dim3(1024), dim3(256), 0, stream>>>(Ap, qws, kws);
  attn_kernel<<<dim3(NTASK / 256), dim3(256), 0, stream>>>(flows, qws, kws, out);
}